// Round 6
// baseline (7056.081 us; speedup 1.0000x reference)
//
#include <hip/hip_runtime.h>

// LSTM b=32, t=1024, din=512, hid=1024. Persistent cooperative kernel.
//
// R9 = R8's batch-split + tagged-data transport, with R8's three confounds
// removed:
//  (1) wave specialization RESTORED: waves 0-3 "G" do gather->pointwise->
//      publish->out->x-MFMA; waves 4-7 "H" do poll->cvt->h-MFMA. Consumer
//      poll overlaps producer pointwise (R8 summed them serially).
//  (2) publish has NO preceding wait_vm0 and precedes the out store.
//      Same-address ordering is causal: v(t+3) is issued only after v(t+1)
//      was OBSERVED at L3 by every consumer (publish<-gates<-consume chain),
//      so the old value reached L3 before the new store exists. R8's
//      wait_vm0 stalled on the previous out-store's HBM completion.
//  (3) adaptive pre-poll sleep (bang-bang +/-) so poll round 1 lands just
//      after visibility: ~1 round/step -> poll L3 traffic ~= payload
//      (8 MB/step, half of R8's; wasted full rounds re-read everything).
//  - 128 blocks = 2 independent 64-block systems (batch halves of 16).
//    Block (p,ug) owns 16 batches x 16 units. M=16 MFMA tiles.
//  - h as f32, step-tag in mantissa LSB (2^-23; invisible after bf16 cvt).
//    Publish = ONE sc1 store/thread. No flags, no acks, no separate load.
//  - Selective re-read: per-16B-chunk freshness, retries touch stale only.
//  - ONE barrier/step (red ping-pong [2][8][16x68] f32).
//  - ABA: slot=n&1, tag=(n>>1)&1; skew bound <=1 version per system.
//  - single wb[8][4] register array for both roles (G uses [0..3]) so
//    divergent allocation doesn't double the weight cost; lb(512,1) since
//    128 blocks on 256 CUs = 1 block/CU anyway -> 256 VGPR/wave budget.

#define T_STEPS 1024
#define BATCH   32
#define DIN     512
#define HID     1024
#define KTOT    1536
#define NBLK    128
#define RSTR    68            // f32 row stride in red (64 cols + 4 pad)
#define REDW    (16*RSTR)     // 1088 floats per wave slot
#define NSLOT   8
#define HSLOT   32768         // f32 words per slot: [32 batch rows][1024 units]

typedef __attribute__((ext_vector_type(8))) short  short8;
typedef __attribute__((ext_vector_type(4))) float  floatx4;
typedef __attribute__((ext_vector_type(4))) unsigned int uintx4;
typedef __attribute__((ext_vector_type(4))) unsigned short ushort4_;

#define MFMA16(a,b,c) __builtin_amdgcn_mfma_f32_16x16x32_bf16(a, b, c, 0, 0, 0)

__device__ __forceinline__ unsigned short f2bf(float f) {
    unsigned u = __builtin_bit_cast(unsigned, f);
    u += 0x7FFFu + ((u >> 16) & 1u);
    return (unsigned short)(u >> 16);
}
__device__ __forceinline__ float sigf(float x) { return 1.f / (1.f + __expf(-x)); }
__device__ __forceinline__ float tanh_fast(float x) {
    float e = __expf(2.f * x);
    return 1.f - 2.f / (e + 1.f);
}
// pack 2 f32 -> 2 bf16 in one u32 (RTNE); gfx950 hw instr
__device__ __forceinline__ unsigned cvt2(float a, float b) {
    unsigned r;
    asm("v_cvt_pk_bf16_f32 %0, %1, %2" : "=v"(r) : "v"(a), "v"(b));
    return r;
}

// ---- device-scope (L3 coherence point) access helpers: sc1 ----
__device__ __forceinline__ floatx4 coh_load16f(const void* p) {
    floatx4 v;
    asm volatile("global_load_dwordx4 %0, %1, off sc1" : "=v"(v) : "v"(p));
    return v;
}
__device__ __forceinline__ void coh_store4u(void* p, unsigned v) {
    asm volatile("global_store_dword %0, %1, off sc1" :: "v"(p), "v"(v) : "memory");
}
__device__ __forceinline__ void wait_vm0() {
    asm volatile("s_waitcnt vmcnt(0)" ::: "memory");
}

// ---- prep: kernel [1536][4096] fp32 -> wt [4096 cols][1536 k] bf16 ----
__global__ __launch_bounds__(256) void prep_wt(const float* __restrict__ kern,
                                               unsigned short* __restrict__ wt) {
    __shared__ unsigned short tile[64][72];
    const int c0 = (blockIdx.x & 63) * 64;
    const int k0 = (blockIdx.x >> 6) * 64;
    const int cl = threadIdx.x & 63;
    const int kg = threadIdx.x >> 6;
    #pragma unroll
    for (int i = 0; i < 16; ++i) {
        int kl = kg * 16 + i;
        tile[cl][kl] = f2bf(kern[(k0 + kl) * 4096 + c0 + cl]);
    }
    __syncthreads();
    #pragma unroll
    for (int i = 0; i < 16; ++i) {
        int cc = kg * 16 + i;
        wt[(size_t)(c0 + cc) * KTOT + k0 + cl] = tile[cc][cl];
    }
}

// ---- prep: x [32][1024][512] fp32 -> xT [1024][32][512] bf16 ----
__global__ __launch_bounds__(256) void prep_x(const float* __restrict__ x,
                                              unsigned short* __restrict__ xT) {
    const int row = blockIdx.x * 2 + (threadIdx.x >> 7);
    const int l   = threadIdx.x & 127;
    const int b = row >> 10, t = row & 1023;
    float4 v = ((const float4*)(x + (size_t)row * DIN))[l];
    ushort4_ o;
    o.x = f2bf(v.x); o.y = f2bf(v.y); o.z = f2bf(v.z); o.w = f2bf(v.w);
    *(ushort4_*)(xT + ((size_t)t * BATCH + b) * DIN + l * 4) = o;
}

// ---- prep: h0(f32, tag0) -> slot0 rows [32][1024]; slot1 poisoned stale ----
__global__ __launch_bounds__(256) void init_h(const float* __restrict__ h_init,
                                              unsigned* __restrict__ hbuf_u) {
    const int idx = blockIdx.x * 256 + threadIdx.x;   // 0..32767
    const int uu = idx & 1023;
    hbuf_u[idx] = __builtin_bit_cast(unsigned, h_init[uu]) & ~1u;  // v0 tag0
    hbuf_u[HSLOT + idx] = 1u;                                      // stale for v1
}

// ---- persistent LSTM ----
__global__ __launch_bounds__(512, 1) void lstm_persist(
    const unsigned short* __restrict__ wt,   // [4096 cols][1536 k] bf16
    const unsigned short* __restrict__ xT,   // [1024][32][512] bf16
    float* __restrict__ hbuf,                // [2][32][1024] f32 tagged
    const float* __restrict__ bias,          // [4096]
    float* __restrict__ out)                 // [32][1024][1024] fp32
{
    __shared__ float red[2][NSLOT][REDW];    // 69,632 B ping-pong accumulators

    const int bk   = blockIdx.x;
    const int p    = bk >> 6;      // batch half (independent system)
    const int ug   = bk & 63;      // unit group: units [ug*16, ug*16+16)
    const int tid  = threadIdx.x;
    const int wave = tid >> 6;
    const int lane = tid & 63;
    const int lrow = lane & 15;
    const int kq   = lane >> 4;
    const bool isG = wave < 4;

    unsigned* hbuf_u = (unsigned*)hbuf;

    // ---- persistent weights in registers; single array for both roles ----
    // G wave w: slices [0..3] = x-k w*128 + i*32 + kq*8
    // H wave wh: slices [0..7] = h-k 512 + wh*256 + j*32 + kq*8
    short8 wb[8][4];
    if (isG) {
        #pragma unroll
        for (int nf = 0; nf < 4; ++nf) {
            const size_t gcol = (size_t)(nf * HID + ug * 16 + lrow) * KTOT;
            #pragma unroll
            for (int i = 0; i < 4; ++i)
                wb[i][nf] = *(const short8*)(wt + gcol + wave * 128 + i * 32 + kq * 8);
        }
    } else {
        const int wh = wave - 4;
        #pragma unroll
        for (int nf = 0; nf < 4; ++nf) {
            const size_t gcol = (size_t)(nf * HID + ug * 16 + lrow) * KTOT;
            #pragma unroll
            for (int j = 0; j < 8; ++j)
                wb[j][nf] = *(const short8*)(wt + gcol + 512 + wh * 256 + j * 32 + kq * 8);
        }
    }

    // pointwise mapping (tid<256): batch pb (0..15), unit pu (0..15)
    const int pb = tid >> 4;
    const int pu = tid & 15;
    float bias_r[4], c_state = 0.f;
    if (tid < 256) {
        #pragma unroll
        for (int g = 0; g < 4; ++g) bias_r[g] = bias[g * HID + ug * 16 + pu];
    }

    // H lane h-source offset within a slot: row (p*16+lrow), k wh*256+kq*8
    const int hoff = (p * 16 + lrow) * HID + (wave - 4) * 256 + kq * 8;

    floatx4 xa[4];

    // ---- prologue: gates(0) -> red[0]; G prefetches x(1) ----
    {
        const floatx4 zero = {0.f, 0.f, 0.f, 0.f};
        floatx4 acc[4] = {zero, zero, zero, zero};
        if (isG) {
            const unsigned short* xb = xT + (size_t)(p * 16 + lrow) * DIN;  // t=0
            #pragma unroll
            for (int i = 0; i < 4; ++i) {
                short8 a = *(const short8*)(xb + wave * 128 + i * 32 + kq * 8);
                #pragma unroll
                for (int nf = 0; nf < 4; ++nf) acc[nf] = MFMA16(a, wb[i][nf], acc[nf]);
            }
            const unsigned short* xn = xT + ((size_t)1 * BATCH + p * 16 + lrow) * DIN;
            #pragma unroll
            for (int i = 0; i < 4; ++i)
                xa[i] = *(const floatx4*)(xn + wave * 128 + i * 32 + kq * 8);
        } else {
            // v0 guaranteed fresh by init_h (kernel-boundary coherence)
            floatx4 hf[8][2];
            #pragma unroll
            for (int j = 0; j < 8; ++j) {
                hf[j][0] = coh_load16f(hbuf + hoff + j * 32);
                hf[j][1] = coh_load16f(hbuf + hoff + j * 32 + 4);
            }
            wait_vm0();
            __builtin_amdgcn_sched_barrier(0);
            #pragma unroll
            for (int j = 0; j < 8; ++j) {
                union { short8 s; unsigned u[4]; } wa;
                wa.u[0] = cvt2(hf[j][0][0], hf[j][0][1]);
                wa.u[1] = cvt2(hf[j][0][2], hf[j][0][3]);
                wa.u[2] = cvt2(hf[j][1][0], hf[j][1][1]);
                wa.u[3] = cvt2(hf[j][1][2], hf[j][1][3]);
                #pragma unroll
                for (int nf = 0; nf < 4; ++nf) acc[nf] = MFMA16(wa.s, wb[j][nf], acc[nf]);
            }
        }
        #pragma unroll
        for (int nf = 0; nf < 4; ++nf)
            #pragma unroll
            for (int r = 0; r < 4; ++r)
                red[0][wave][(kq * 4 + r) * RSTR + nf * 16 + lrow] = acc[nf][r];
    }

    int slp = 8;   // adaptive pre-poll sleep, ~64cy units (H waves, uniform)

    for (int t = 0; t < T_STEPS; ++t) {
        __syncthreads();    // A(t): red[t&1] complete (the only barrier/step)

        const float* rc = &red[t & 1][0][0];
        float*       rn = &red[(t + 1) & 1][0][0];
        const unsigned tg = ((unsigned)(t + 1) >> 1) & 1u;  // tag of v(t+1)
        const int      so = ((t + 1) & 1) * HSLOT;          // slot of v(t+1)

        if (tid < 256) {
            // ---- G: gather 8 slots x 4 gates, activate, publish, out ----
            float gv[4];
            #pragma unroll
            for (int g = 0; g < 4; ++g) {
                float s = bias_r[g];
                #pragma unroll
                for (int wv = 0; wv < NSLOT; ++wv)
                    s += rc[wv * REDW + pb * RSTR + g * 16 + pu];
                gv[g] = s;
            }
            const float fg = sigf(gv[0]);
            const float ig = sigf(gv[1]);
            const float og = sigf(gv[2]);
            const float gg = tanh_fast(gv[3]);
            c_state = fg * c_state + ig * gg;
            const float hn = og * tanh_fast(c_state);

            if (t + 1 < T_STEPS) {
                // publish FIRST, no pre-wait (same-address order is causal)
                unsigned hv = (__builtin_bit_cast(unsigned, hn) & ~1u) | tg;
                coh_store4u(hbuf_u + so + (p * 16 + pb) * HID + ug * 16 + pu, hv);
            }
            out[(size_t)(p * 16 + pb) * (T_STEPS * HID) + (size_t)t * HID
                + ug * 16 + pu] = hn;
        }

        if (t + 1 == T_STEPS) break;   // uniform

        const floatx4 zero = {0.f, 0.f, 0.f, 0.f};
        floatx4 acc[4] = {zero, zero, zero, zero};

        if (isG) {
            // ---- G: x-part MFMA for gates(t+1); red write; prefetch ----
            #pragma unroll
            for (int i = 0; i < 4; ++i) {
                short8 a = __builtin_bit_cast(short8, xa[i]);
                #pragma unroll
                for (int nf = 0; nf < 4; ++nf) acc[nf] = MFMA16(a, wb[i][nf], acc[nf]);
            }
            #pragma unroll
            for (int nf = 0; nf < 4; ++nf)
                #pragma unroll
                for (int r = 0; r < 4; ++r)
                    rn[wave * REDW + (kq * 4 + r) * RSTR + nf * 16 + lrow] = acc[nf][r];
            if (t + 2 < T_STEPS) {
                const unsigned short* xn =
                    xT + ((size_t)(t + 2) * BATCH + p * 16 + lrow) * DIN;
                #pragma unroll
                for (int i = 0; i < 4; ++i)
                    xa[i] = *(const floatx4*)(xn + wave * 128 + i * 32 + kq * 8);
            }
        } else {
            // ---- H: adaptive sleep, poll v(t+1), selective re-read ----
            for (int s = slp; s > 0; --s) __builtin_amdgcn_s_sleep(1);
            const float* hb = hbuf + so + hoff;
            floatx4 hf[8][2];
            #pragma unroll
            for (int j = 0; j < 8; ++j) {
                hf[j][0] = coh_load16f(hb + j * 32);
                hf[j][1] = coh_load16f(hb + j * 32 + 4);
            }
            wait_vm0();
            __builtin_amdgcn_sched_barrier(0);
            unsigned stale = 0;
            #pragma unroll
            for (int j = 0; j < 8; ++j)
                #pragma unroll
                for (int c2 = 0; c2 < 2; ++c2) {
                    uintx4 u = __builtin_bit_cast(uintx4, hf[j][c2]);
                    unsigned fr = tg ? (u[0] & u[1] & u[2] & u[3])
                                     : ~(u[0] | u[1] | u[2] | u[3]);
                    if (!(fr & 1u)) stale |= 1u << (j * 2 + c2);
                }
            int rounds = 1;
            while (__any((int)(stale != 0u))) {
                ++rounds;
                #pragma unroll
                for (int j = 0; j < 8; ++j)
                    #pragma unroll
                    for (int c2 = 0; c2 < 2; ++c2)
                        if (stale & (1u << (j * 2 + c2)))
                            hf[j][c2] = coh_load16f(hb + j * 32 + c2 * 4);
                wait_vm0();
                __builtin_amdgcn_sched_barrier(0);
                unsigned ns = 0;
                #pragma unroll
                for (int j = 0; j < 8; ++j)
                    #pragma unroll
                    for (int c2 = 0; c2 < 2; ++c2)
                        if (stale & (1u << (j * 2 + c2))) {
                            uintx4 u = __builtin_bit_cast(uintx4, hf[j][c2]);
                            unsigned fr = tg ? (u[0] & u[1] & u[2] & u[3])
                                             : ~(u[0] | u[1] | u[2] | u[3]);
                            if (!(fr & 1u)) ns |= 1u << (j * 2 + c2);
                        }
                stale = ns;
            }
            // bang-bang adapt toward ~1 round/step (uniform across wave)
            if (rounds == 1) { if (slp > 0) --slp; }
            else { slp += 2 * (rounds - 1); if (slp > 48) slp = 48; }

            // ---- cvt + h-part MFMA; red write ----
            #pragma unroll
            for (int j = 0; j < 8; ++j) {
                union { short8 s; unsigned u[4]; } wa;
                wa.u[0] = cvt2(hf[j][0][0], hf[j][0][1]);
                wa.u[1] = cvt2(hf[j][0][2], hf[j][0][3]);
                wa.u[2] = cvt2(hf[j][1][0], hf[j][1][1]);
                wa.u[3] = cvt2(hf[j][1][2], hf[j][1][3]);
                #pragma unroll
                for (int nf = 0; nf < 4; ++nf) acc[nf] = MFMA16(wa.s, wb[j][nf], acc[nf]);
            }
            #pragma unroll
            for (int nf = 0; nf < 4; ++nf)
                #pragma unroll
                for (int r = 0; r < 4; ++r)
                    rn[wave * REDW + (kq * 4 + r) * RSTR + nf * 16 + lrow] = acc[nf][r];
        }
    }
}

extern "C" void kernel_launch(void* const* d_in, const int* in_sizes, int n_in,
                              void* d_out, int out_size, void* d_ws, size_t ws_size,
                              hipStream_t stream) {
    (void)in_sizes; (void)n_in; (void)out_size;
    const float* x      = (const float*)d_in[0];
    // d_in[1] = input_paddings (all zero, unused per reference)
    const float* kern   = (const float*)d_in[2];
    const float* bias   = (const float*)d_in[3];
    const float* h_init = (const float*)d_in[4];
    float* out = (float*)d_out;

    char* ws = (char*)d_ws;
    unsigned short* wt   = (unsigned short*)(ws);                       // 12,582,912 B
    unsigned short* xT   = (unsigned short*)(ws + 12582912);            // 33,554,432 B
    float*          hbuf = (float*)(ws + 12582912 + 33554432);          //    262,144 B
    (void)ws_size;

    prep_wt<<<dim3(64 * 24), dim3(256), 0, stream>>>(kern, wt);
    prep_x<<<dim3(BATCH * T_STEPS / 2), dim3(256), 0, stream>>>(x, xT);
    init_h<<<dim3(128), dim3(256), 0, stream>>>(h_init, (unsigned*)hbuf);

    void* args[] = { &wt, &xT, &hbuf, &bias, &out };
    hipLaunchCooperativeKernel((const void*)lstm_persist, dim3(NBLK), dim3(512),
                               args, 0, stream);
}